// Round 6
// baseline (394.930 us; speedup 1.0000x reference)
//
#include <hip/hip_runtime.h>
#include <cmath>

namespace {
constexpr int B = 8;
constexpr int T = 2048;
constexpr int D = 512;
constexpr int S = 2048;
constexpr int R = 64;
constexpr int KTOP = 16;
constexpr int NT = 8;    // tokens per block in score kernel (512 threads)
constexpr int NI = 8;    // rows per block in pscore kernel (512 threads)
constexpr int CAP = 256;     // bin capacity per (b,slot); overflow -> global list
constexpr int OVFCAP = 32768;

__device__ __forceinline__ float signf(float v) {
    return (v > 0.f) ? 1.f : ((v < 0.f) ? -1.f : 0.f);
}

// Exact top-16 by |value| (ties -> lower index) over a wave-private LDS row of S
// floats. Result: lane k (k<16) gets myg = signed value, myj = index, in exact
// descending (|v|, -j) order. Row contents are preserved on the fast path.
__device__ __forceinline__ void topk16_row(float* __restrict__ row,
                                           unsigned long long* __restrict__ cand,
                                           int lane, float& myg, int& myj) {
    const float4* p4 = (const float4*)row;
    // Phase 1: per-lane abs max over 32 elements
    float lmax = 0.f;
#pragma unroll
    for (int i = 0; i < 8; i++) {
        float4 v = p4[lane + 64 * i];
        lmax = fmaxf(lmax, fmaxf(fmaxf(fabsf(v.x), fabsf(v.y)),
                                 fmaxf(fabsf(v.z), fabsf(v.w))));
    }
    // Phase 2: bitonic sort (descending) of 64 lane maxes; t = 16th largest
    {
        float v = lmax;
#pragma unroll
        for (int size = 2; size <= 64; size <<= 1) {
#pragma unroll
            for (int stride = size >> 1; stride > 0; stride >>= 1) {
                float o = __shfl_xor(v, stride, 64);
                bool takeMax = ((lane & size) == 0) == ((lane & stride) == 0);
                v = takeMax ? fmaxf(v, o) : fminf(v, o);
            }
        }
        lmax = __shfl(v, 15);
    }
    float t = lmax;
    // Phase 3: count candidates with |v| >= t, prefix-sum, compact into cand[]
    int cnt = 0;
#pragma unroll
    for (int i = 0; i < 8; i++) {
        float4 v = p4[lane + 64 * i];
        cnt += (fabsf(v.x) >= t) + (fabsf(v.y) >= t) +
               (fabsf(v.z) >= t) + (fabsf(v.w) >= t);
    }
    int off = cnt;
#pragma unroll
    for (int d = 1; d < 64; d <<= 1) {
        int o = __shfl_up(off, d, 64);
        if (lane >= d) off += o;
    }
    int total = __shfl(off, 63);
    int base = off - cnt;

    if (total <= 64) {
        int pos = base;
#pragma unroll
        for (int i = 0; i < 8; i++) {
            float4 v = p4[lane + 64 * i];
            int jb = 4 * (lane + 64 * i);
            float c[4] = {v.x, v.y, v.z, v.w};
#pragma unroll
            for (int cc = 0; cc < 4; cc++) {
                if (fabsf(c[cc]) >= t) {
                    unsigned ab = __float_as_uint(c[cc]) & 0x7fffffffu;
                    cand[pos++] = ((unsigned long long)ab << 11) |
                                  (unsigned)(2047 - (jb + cc));
                }
            }
        }
        // Phase 4: bitonic sort (descending) of up to 64 u64 keys
        unsigned long long key = (lane < total) ? cand[lane] : 0ull;
#pragma unroll
        for (int size = 2; size <= 64; size <<= 1) {
#pragma unroll
            for (int stride = size >> 1; stride > 0; stride >>= 1) {
                unsigned long long o = __shfl_xor((long long)key, stride, 64);
                bool takeMax = ((lane & size) == 0) == ((lane & stride) == 0);
                key = (takeMax == (key > o)) ? key : o;
            }
        }
        myg = 0.f; myj = 0;
        if (lane < KTOP) {
            myj = 2047 - (int)(key & 2047ull);
            myg = row[myj];
        }
    } else {
        // Fallback (rare): 16 rounds of full-row argmax with removal
        myg = 0.f; myj = 0;
        for (int k = 0; k < KTOP; k++) {
            float bv = -1.f, bs = 0.f; int bj = 0;
#pragma unroll
            for (int i = 0; i < 8; i++) {
                float4 v = p4[lane + 64 * i];
                int jb = 4 * (lane + 64 * i);
                { float a = fabsf(v.x); if (a > bv) { bv = a; bs = v.x; bj = jb; } }
                { float a = fabsf(v.y); if (a > bv) { bv = a; bs = v.y; bj = jb + 1; } }
                { float a = fabsf(v.z); if (a > bv) { bv = a; bs = v.z; bj = jb + 2; } }
                { float a = fabsf(v.w); if (a > bv) { bv = a; bs = v.w; bj = jb + 3; } }
            }
#pragma unroll
            for (int off2 = 32; off2 > 0; off2 >>= 1) {
                float ov = __shfl_xor(bv, off2, 64);
                float os = __shfl_xor(bs, off2, 64);
                int   oj = __shfl_xor(bj, off2, 64);
                if (ov > bv || (ov == bv && oj < bj)) { bv = ov; bs = os; bj = oj; }
            }
            if (lane == k) { myg = bs; myj = bj; }
            if (lane == 0) row[bj] = 0.f;
        }
    }
}
} // namespace

// ---------- score stage: route scores -> per-wave topk -> bin lists ----------
// state_ws holds DELTAS only (memset 0 before this kernel).
// Overflow (bin > CAP) goes to a global list consumed by k_accum_qk.
__global__ void __launch_bounds__(512, 4) k_score(const float* __restrict__ x,
                                                  const float* __restrict__ route_a,
                                                  const float* __restrict__ route_b,
                                                  float* __restrict__ state_ws,
                                                  float* __restrict__ coef,
                                                  int* __restrict__ bincount,
                                                  int* __restrict__ binlist,
                                                  int* __restrict__ ovf_cnt,
                                                  int* __restrict__ ovf_key,
                                                  float* __restrict__ ovf_c) {
    __shared__ __align__(16) char smem[NT * S * 4]; // 64 KB: xs -> red4 -> sc
    __shared__ __align__(16) float xr[NT][R];       // 2 KB
    __shared__ unsigned long long cand[NT][64];     // 4 KB
    float (*sc)[S] = (float(*)[S])smem;
    float (*xs)[D] = (float(*)[D])smem;             // overlay (x-load + acc read)
    float (*red4)[512] = (float(*)[512])smem;       // overlay (reduction only)

    int tid = threadIdx.x;
    int lane = tid & 63, wv = tid >> 6;
    int blk = ((blockIdx.x & 7) << 8) | (blockIdx.x >> 3);  // XCD k <-> b=k
    int tb = blk * NT;              // global token base (block never straddles b)
    int b = tb >> 11;               // T = 2048
    int t0 = tb & (T - 1);

    // load 8 x rows into LDS (1024 float4, 512 threads)
    {
        const float4* xg = (const float4*)(x + (size_t)tb * D);
        float4* xls = (float4*)smem;
        xls[tid] = xg[tid];
        xls[tid + 512] = xg[tid + 512];
    }
    __syncthreads();

    // x inverse norm for this wave's token, from LDS (x is read once, here)
    float xinv;
    {
        const float4* xst = (const float4*)&xs[wv][0];
        float4 x0 = xst[lane], x1 = xst[lane + 64];
        float ssx = x0.x * x0.x + x0.y * x0.y + x0.z * x0.z + x0.w * x0.w
                  + x1.x * x1.x + x1.y * x1.y + x1.z * x1.z + x1.w * x1.w;
#pragma unroll
        for (int off = 32; off > 0; off >>= 1) ssx += __shfl_xor(ssx, off, 64);
        xinv = 1.0f / (sqrtf(ssx) + 1e-6f);
    }

    // xr = x . route_a  (wave wv covers d in [wv*64, wv*64+64), r = lane)
    {
        int r = lane;
        float acc[NT];
#pragma unroll
        for (int tt = 0; tt < NT; tt++) acc[tt] = 0.f;
        for (int d0 = wv * 64; d0 < wv * 64 + 64; d0 += 4) {
            float a0 = route_a[(size_t)(d0 + 0) * R + r];
            float a1 = route_a[(size_t)(d0 + 1) * R + r];
            float a2 = route_a[(size_t)(d0 + 2) * R + r];
            float a3 = route_a[(size_t)(d0 + 3) * R + r];
#pragma unroll
            for (int tt = 0; tt < NT; tt++) {
                float4 xv = *(const float4*)&xs[tt][d0];
                acc[tt] += xv.x * a0 + xv.y * a1 + xv.z * a2 + xv.w * a3;
            }
        }
        __syncthreads();   // xs dead; red4 region writable
#pragma unroll
        for (int tt = 0; tt < NT; tt++) red4[tt][tid] = acc[tt];
        __syncthreads();
        {
            int tt2 = tid >> 6, r2 = tid & 63;
            float s = 0.f;
#pragma unroll
            for (int g = 0; g < 8; g++) s += red4[tt2][g * 64 + r2];
            xr[tt2][r2] = s;
        }
        __syncthreads();   // red4 dead; sc writable
    }

    // scores = xr . route_b  (float4 over s; 512 threads cover S/4 = 512)
    {
        const float4* rb4 = (const float4*)route_b;
        int j4 = tid;
        float4 acc[NT];
#pragma unroll
        for (int tt = 0; tt < NT; tt++) acc[tt] = make_float4(0.f, 0.f, 0.f, 0.f);
        for (int r0 = 0; r0 < R; r0 += 4) {
            float4 xv[NT];
#pragma unroll
            for (int tt = 0; tt < NT; tt++) xv[tt] = *(const float4*)&xr[tt][r0];
#define SCORE_STEP(dr, comp)                                                   \
            {                                                                  \
                float4 bv = rb4[(size_t)(r0 + dr) * (S / 4) + j4];             \
                _Pragma("unroll")                                              \
                for (int tt = 0; tt < NT; tt++) {                              \
                    float c = xv[tt].comp;                                     \
                    acc[tt].x += c * bv.x; acc[tt].y += c * bv.y;              \
                    acc[tt].z += c * bv.z; acc[tt].w += c * bv.w;              \
                }                                                              \
            }
            SCORE_STEP(0, x) SCORE_STEP(1, y) SCORE_STEP(2, z) SCORE_STEP(3, w)
#undef SCORE_STEP
        }
#pragma unroll
        for (int tt = 0; tt < NT; tt++)
            ((float4*)&sc[tt][0])[j4] = acc[tt];
    }
    __syncthreads();

    // ---- per-wave from here: wave wv owns token tt = wv ----
    int tt = wv;
    int tloc = t0 + tt;
    int tglob = tb + tt;

    float myg; int myj;
    topk16_row(&sc[tt][0], &cand[wv][0], lane, myg, myj);

    // signed-abs-softmax over the 16 winners (lane k holds winner k)
    float m = __shfl(fabsf(myg), 0);
    float e = (lane < KTOP) ? expf(fabsf(myg) - m) : 0.f;
    float esum = e;
#pragma unroll
    for (int off = 8; off > 0; off >>= 1) esum += __shfl_xor(esum, off, 64);
    esum = __shfl(esum, 0);
    float w = signf(myg) * e / esum;
    float coefv = w * xinv;

    if (lane < KTOP) {
        float sp = (myg > 20.f) ? myg : log1pf(expf(myg));
        atomicAdd(&state_ws[(size_t)b * S + myj], sp);
        int pos = atomicAdd(&bincount[(size_t)b * S + myj], 1);
        if (pos < CAP) {
            binlist[((size_t)b * S + myj) * CAP + pos] = (tloc << 4) | lane;
            coef[(size_t)tglob * KTOP + lane] = coefv;
        } else {
            // overflow (essentially never): append to global list
            int i = atomicAdd(ovf_cnt, 1);
            if (i < OVFCAP) {
                ovf_key[i] = ((b * S + myj) << 11) | tloc;  // 14b row | 11b tloc
                ovf_c[i] = coefv;
            }
        }
    }
}

// ---------- accum+qk: val1 = unit_norm(base + sum c*x); q/kkT projections ----
// Gather loop uses 4-wide load batching (4 rows' loads in flight, accumulated
// in original order -> bit-identical) to break the L2-latency chain.
__global__ void __launch_bounds__(256) k_accum_qk(const float* __restrict__ x,
                                                  const float* __restrict__ init_val,
                                                  const float* __restrict__ coef,
                                                  const int* __restrict__ bincount,
                                                  const int* __restrict__ binlist,
                                                  const int* __restrict__ ovf_cnt,
                                                  const int* __restrict__ ovf_key,
                                                  const float* __restrict__ ovf_c,
                                                  const float* __restrict__ pair_a,
                                                  const float* __restrict__ pair_b,
                                                  float* __restrict__ val1,
                                                  float* __restrict__ q,
                                                  float* __restrict__ kkT) {
    __shared__ __align__(16) float vrow[4][D];    // 8 KB
    __shared__ float redq[4][256];                // 4 KB
    __shared__ float redk[4][256];                // 4 KB

    int tid = threadIdx.x;
    int lane = tid & 63, wv = tid >> 6;
    int blk = ((blockIdx.x & 7) << 9) | (blockIdx.x >> 3);  // XCD k <-> b=k
    int rowbase = blk * 4;
    int row = rowbase + wv;             // row = b*S + s
    int b = row >> 11;                  // S = 2048
    int s_idx = row & (S - 1);
    int sbase = rowbase & (S - 1);

    // base = unit_norm(init_val[s]) computed in-register
    const float4* src = (const float4*)(init_val + (size_t)s_idx * D);
    float4 a0 = src[lane], a1 = src[lane + 64];
    {
        float ss0 = a0.x * a0.x + a0.y * a0.y + a0.z * a0.z + a0.w * a0.w
                  + a1.x * a1.x + a1.y * a1.y + a1.z * a1.z + a1.w * a1.w;
#pragma unroll
        for (int off = 32; off > 0; off >>= 1) ss0 += __shfl_xor(ss0, off, 64);
        float bsc = 1.0f / (sqrtf(ss0) + 1e-6f);
        a0.x *= bsc; a0.y *= bsc; a0.z *= bsc; a0.w *= bsc;
        a1.x *= bsc; a1.y *= bsc; a1.z *= bsc; a1.w *= bsc;
    }

    const float* xb = x + (size_t)b * T * D;
    int n = bincount[row]; if (n > CAP) n = CAP;
    const int* lp = binlist + (size_t)row * CAP;
    for (int base = 0; base < n; base += 64) {
        int mm = n - base; if (mm > 64) mm = 64;
        int ent = 0; float cc = 0.f;
        if (lane < mm) {
            ent = lp[base + lane];
            cc = coef[((size_t)b * T + (ent >> 4)) * KTOP + (ent & 15)];
        }
        int k = 0;
        // 4-wide batches: 8 float4 loads in flight, accumulate in k-order
        for (; k + 4 <= mm; k += 4) {
            int j0 = __shfl(ent, k) >> 4,     j1 = __shfl(ent, k + 1) >> 4;
            int j2 = __shfl(ent, k + 2) >> 4, j3 = __shfl(ent, k + 3) >> 4;
            float c0 = __shfl(cc, k),     c1 = __shfl(cc, k + 1);
            float c2 = __shfl(cc, k + 2), c3 = __shfl(cc, k + 3);
            const float4* p0 = (const float4*)(xb + (size_t)j0 * D);
            const float4* p1 = (const float4*)(xb + (size_t)j1 * D);
            const float4* p2 = (const float4*)(xb + (size_t)j2 * D);
            const float4* p3 = (const float4*)(xb + (size_t)j3 * D);
            float4 u0 = p0[lane], u1 = p0[lane + 64];
            float4 u2 = p1[lane], u3 = p1[lane + 64];
            float4 u4 = p2[lane], u5 = p2[lane + 64];
            float4 u6 = p3[lane], u7 = p3[lane + 64];
            a0.x += c0 * u0.x; a0.y += c0 * u0.y; a0.z += c0 * u0.z; a0.w += c0 * u0.w;
            a1.x += c0 * u1.x; a1.y += c0 * u1.y; a1.z += c0 * u1.z; a1.w += c0 * u1.w;
            a0.x += c1 * u2.x; a0.y += c1 * u2.y; a0.z += c1 * u2.z; a0.w += c1 * u2.w;
            a1.x += c1 * u3.x; a1.y += c1 * u3.y; a1.z += c1 * u3.z; a1.w += c1 * u3.w;
            a0.x += c2 * u4.x; a0.y += c2 * u4.y; a0.z += c2 * u4.z; a0.w += c2 * u4.w;
            a1.x += c2 * u5.x; a1.y += c2 * u5.y; a1.z += c2 * u5.z; a1.w += c2 * u5.w;
            a0.x += c3 * u6.x; a0.y += c3 * u6.y; a0.z += c3 * u6.z; a0.w += c3 * u6.w;
            a1.x += c3 * u7.x; a1.y += c3 * u7.y; a1.z += c3 * u7.z; a1.w += c3 * u7.w;
        }
        for (; k < mm; k++) {
            int j0 = __shfl(ent, k) >> 4;
            float c = __shfl(cc, k);
            const float4* p0 = (const float4*)(xb + (size_t)j0 * D);
            float4 u0 = p0[lane], u1 = p0[lane + 64];
            a0.x += c * u0.x; a0.y += c * u0.y; a0.z += c * u0.z; a0.w += c * u0.w;
            a1.x += c * u1.x; a1.y += c * u1.y; a1.z += c * u1.z; a1.w += c * u1.w;
        }
    }

    // overflow list (cold path; one uniform load when empty)
    int oc = *ovf_cnt; if (oc > OVFCAP) oc = OVFCAP;
    for (int i = 0; i < oc; i++) {
        int key = ovf_key[i];
        if ((key >> 11) == row) {
            float c = ovf_c[i];
            int tg = ((row >> 11) << 11) | (key & 2047);   // b*T + tloc
            const float4* xp4 = (const float4*)(x + (size_t)tg * D);
            float4 v0 = xp4[lane], v1 = xp4[lane + 64];
            a0.x += c * v0.x; a0.y += c * v0.y; a0.z += c * v0.z; a0.w += c * v0.w;
            a1.x += c * v1.x; a1.y += c * v1.y; a1.z += c * v1.z; a1.w += c * v1.w;
        }
    }

    float ss = a0.x * a0.x + a0.y * a0.y + a0.z * a0.z + a0.w * a0.w
             + a1.x * a1.x + a1.y * a1.y + a1.z * a1.z + a1.w * a1.w;
#pragma unroll
    for (int off = 32; off > 0; off >>= 1) ss += __shfl_xor(ss, off, 64);
    float sc = 1.0f / (sqrtf(ss) + 1e-6f);
    a0.x *= sc; a0.y *= sc; a0.z *= sc; a0.w *= sc;
    a1.x *= sc; a1.y *= sc; a1.z *= sc; a1.w *= sc;
    float4* vp4 = (float4*)(val1 + (size_t)row * D);
    vp4[lane] = a0; vp4[lane + 64] = a1;

    // ---- stage rows to LDS, then q/kT projection (k_qk structure, NR=4) ----
    {
        float4* vr = (float4*)&vrow[wv][0];
        vr[lane] = a0; vr[lane + 64] = a1;
    }
    __syncthreads();

    int r = lane, grp = wv;
    float accq[4], acck[4];
#pragma unroll
    for (int rr = 0; rr < 4; rr++) { accq[rr] = 0.f; acck[rr] = 0.f; }
    for (int d0 = grp * 128; d0 < grp * 128 + 128; d0 += 4) {
#pragma unroll
        for (int dd = 0; dd < 4; dd++) {
            float a  = pair_a[(size_t)(d0 + dd) * R + r];
            float bb = pair_b[(size_t)(d0 + dd) * R + r];
#pragma unroll
            for (int rr = 0; rr < 4; rr++) {
                float v = vrow[rr][d0 + dd];
                accq[rr] += v * a;
                acck[rr] += v * bb;
            }
        }
    }
#pragma unroll
    for (int rr = 0; rr < 4; rr++) {
        redq[rr][tid] = accq[rr];
        redk[rr][tid] = acck[rr];
    }
    __syncthreads();
    {
        int rr = tid >> 6, r2 = tid & 63;
        float qv = redq[rr][r2] + redq[rr][64 + r2] +
                   redq[rr][128 + r2] + redq[rr][192 + r2];
        float kv = redk[rr][r2] + redk[rr][64 + r2] +
                   redk[rr][128 + r2] + redk[rr][192 + r2];
        q[(size_t)(rowbase + rr) * R + r2] = qv;
        kkT[((size_t)b * R + r2) * S + (sbase + rr)] = kv;
    }
}

// ---------- state reduce: base softmax + per-b (m, 1/sum) of base+delta ------
// One block, 512 threads.
__global__ void __launch_bounds__(512) k_state_red(const float* __restrict__ init_state,
                                                   const float* __restrict__ state_ws,
                                                   float* base_ws,
                                                   float* sm_m, float* sm_inv) {
    __shared__ float red[16];
    __shared__ float base_lds[S];   // 8 KB
    int tid = threadIdx.x, lane = tid & 63, wv = tid >> 6;

    // Phase A: base = sign * softmax(|init_state|)  (2048 values, 4 per thread)
    float4 v = ((const float4*)init_state)[tid];
    float m = fmaxf(fmaxf(fabsf(v.x), fabsf(v.y)), fmaxf(fabsf(v.z), fabsf(v.w)));
#pragma unroll
    for (int off = 32; off > 0; off >>= 1) m = fmaxf(m, __shfl_xor(m, off, 64));
    if (lane == 0) red[wv] = m;
    __syncthreads();
    float M = red[0];
#pragma unroll
    for (int i = 1; i < 8; i++) M = fmaxf(M, red[i]);
    __syncthreads();
    float s = expf(fabsf(v.x) - M) + expf(fabsf(v.y) - M) +
              expf(fabsf(v.z) - M) + expf(fabsf(v.w) - M);
#pragma unroll
    for (int off = 32; off > 0; off >>= 1) s += __shfl_xor(s, off, 64);
    if (lane == 0) red[wv] = s;
    __syncthreads();
    float SUM = 0.f;
#pragma unroll
    for (int i = 0; i < 8; i++) SUM += red[i];
    float inv = 1.0f / SUM;
    float4 bo;
    bo.x = signf(v.x) * expf(fabsf(v.x) - M) * inv;
    bo.y = signf(v.y) * expf(fabsf(v.y) - M) * inv;
    bo.z = signf(v.z) * expf(fabsf(v.z) - M) * inv;
    bo.w = signf(v.w) * expf(fabsf(v.w) - M) * inv;
    ((float4*)base_ws)[tid] = bo;
    ((float4*)base_lds)[tid] = bo;
    __syncthreads();

    // Phase B: wave wv = b; combined = base + delta; per-b max & expsum
    int b = wv;
    const float4* dp = (const float4*)(state_ws + (size_t)b * S);
    const float4* bp = (const float4*)base_lds;
    float4 c[8];
    float vm = 0.f;
#pragma unroll
    for (int i = 0; i < 8; i++) {
        float4 dv = dp[lane + 64 * i];
        float4 bv = bp[lane + 64 * i];
        c[i].x = bv.x + dv.x; c[i].y = bv.y + dv.y;
        c[i].z = bv.z + dv.z; c[i].w = bv.w + dv.w;
        vm = fmaxf(vm, fmaxf(fmaxf(fabsf(c[i].x), fabsf(c[i].y)),
                             fmaxf(fabsf(c[i].z), fabsf(c[i].w))));
    }
#pragma unroll
    for (int off = 32; off > 0; off >>= 1) vm = fmaxf(vm, __shfl_xor(vm, off, 64));
    float sum = 0.f;
#pragma unroll
    for (int i = 0; i < 8; i++) {
        sum += expf(fabsf(c[i].x) - vm) + expf(fabsf(c[i].y) - vm) +
               expf(fabsf(c[i].z) - vm) + expf(fabsf(c[i].w) - vm);
    }
#pragma unroll
    for (int off = 32; off > 0; off >>= 1) sum += __shfl_xor(sum, off, 64);
    if (lane == 0) { sm_m[b] = vm; sm_inv[b] = 1.0f / sum; }
}

// ---------- pscore+mix: p = q.kT, topk, gather neighbors, write out ----------
// Mix gather uses 4-wide load batching (8 float4 in flight, accumulate in
// k-order -> bit-identical).
__global__ void __launch_bounds__(512) k_pscore_mix(const float* __restrict__ q,
                                                    const float* __restrict__ kkT,
                                                    const float* __restrict__ val1,
                                                    const float* __restrict__ base_ws,
                                                    const float* __restrict__ state_ws,
                                                    const float* __restrict__ sm_m,
                                                    const float* __restrict__ sm_inv,
                                                    float* __restrict__ out) {
    __shared__ __align__(16) float prow[NI][S];   // 64 KB
    __shared__ __align__(16) float qrow[NI][R];   // 2 KB
    __shared__ unsigned long long cand[NI][64];   // 4 KB

    int tid = threadIdx.x;
    int lane = tid & 63, wv = tid >> 6;
    int blk = ((blockIdx.x & 7) << 8) | (blockIdx.x >> 3);  // XCD k <-> b=k
    int ibase = blk * NI;            // global row base (never straddles b)
    int b = ibase >> 11;             // S = 2048

    {
        int rr = tid >> 6, r = tid & 63;
        qrow[rr][r] = q[(size_t)(ibase + rr) * R + r];
    }
    __syncthreads();

    // p rows (float4 over j; kkT slice reused by 8 rows)
    {
        const float4* kk4 = (const float4*)(kkT + (size_t)b * R * S);
        int j4 = tid;                // 512 threads cover S/4 = 512
        float4 acc[NI];
#pragma unroll
        for (int rr = 0; rr < NI; rr++) acc[rr] = make_float4(0.f, 0.f, 0.f, 0.f);
        for (int r0 = 0; r0 < R; r0 += 4) {
            float4 qv[NI];
#pragma unroll
            for (int rr = 0; rr < NI; rr++) qv[rr] = *(const float4*)&qrow[rr][r0];
#define P_STEP(dr, comp)                                                       \
            {                                                                  \
                float4 kv = kk4[(size_t)(r0 + dr) * (S / 4) + j4];             \
                _Pragma("unroll")                                              \
                for (int rr = 0; rr < NI; rr++) {                              \
                    float c = qv[rr].comp;                                     \
                    acc[rr].x += c * kv.x; acc[rr].y += c * kv.y;              \
                    acc[rr].z += c * kv.z; acc[rr].w += c * kv.w;              \
                }                                                              \
            }
            P_STEP(0, x) P_STEP(1, y) P_STEP(2, z) P_STEP(3, w)
#undef P_STEP
        }
#pragma unroll
        for (int rr = 0; rr < NI; rr++)
            ((float4*)&prow[rr][0])[j4] = acc[rr];
    }
    __syncthreads();

    // ---- per-wave topk on row ibase + wv (8 waves, 8 rows) ----
    int row = ibase + wv;
    float myg; int myj;
    topk16_row(&prow[wv][0], &cand[wv][0], lane, myg, myj);

    float m = __shfl(fabsf(myg), 0);
    float e = (lane < KTOP) ? expf(fabsf(myg) - m) : 0.f;
    float esum = e;
#pragma unroll
    for (int off = 8; off > 0; off >>= 1) esum += __shfl_xor(esum, off, 64);
    esum = __shfl(esum, 0);
    float myw = signf(myg) * e / esum;

    // ---- mix: gather neighbors (4-wide batched), residual, unit-norm ----
    const float* vb = val1 + (size_t)b * S * D;
    const float4* self4 = (const float4*)(val1 + (size_t)row * D);
    float4 a0 = self4[lane], a1 = self4[lane + 64];
#pragma unroll
    for (int kb = 0; kb < KTOP; kb += 4) {
        int j0 = __shfl(myj, kb),     j1 = __shfl(myj, kb + 1);
        int j2 = __shfl(myj, kb + 2), j3 = __shfl(myj, kb + 3);
        float w0 = __shfl(myw, kb),     w1 = __shfl(myw, kb + 1);
        float w2 = __shfl(myw, kb + 2), w3 = __shfl(myw, kb + 3);
        const float4* p0 = (const float4*)(vb + (size_t)j0 * D);
        const float4* p1 = (const float4*)(vb + (size_t)j1 * D);
        const float4* p2 = (const float4*)(vb + (size_t)j2 * D);
        const float4* p3 = (const float4*)(vb + (size_t)j3 * D);
        float4 u0 = p0[lane], u1 = p0[lane + 64];
        float4 u2 = p1[lane], u3 = p1[lane + 64];
        float4 u4 = p2[lane], u5 = p2[lane + 64];
        float4 u6 = p3[lane], u7 = p3[lane + 64];
        a0.x += w0 * u0.x; a0.y += w0 * u0.y; a0.z += w0 * u0.z; a0.w += w0 * u0.w;
        a1.x += w0 * u1.x; a1.y += w0 * u1.y; a1.z += w0 * u1.z; a1.w += w0 * u1.w;
        a0.x += w1 * u2.x; a0.y += w1 * u2.y; a0.z += w1 * u2.z; a0.w += w1 * u2.w;
        a1.x += w1 * u3.x; a1.y += w1 * u3.y; a1.z += w1 * u3.z; a1.w += w1 * u3.w;
        a0.x += w2 * u4.x; a0.y += w2 * u4.y; a0.z += w2 * u4.z; a0.w += w2 * u4.w;
        a1.x += w2 * u5.x; a1.y += w2 * u5.y; a1.z += w2 * u5.z; a1.w += w2 * u5.w;
        a0.x += w3 * u6.x; a0.y += w3 * u6.y; a0.z += w3 * u6.z; a0.w += w3 * u6.w;
        a1.x += w3 * u7.x; a1.y += w3 * u7.y; a1.z += w3 * u7.z; a1.w += w3 * u7.w;
    }
    float ss = a0.x * a0.x + a0.y * a0.y + a0.z * a0.z + a0.w * a0.w
             + a1.x * a1.x + a1.y * a1.y + a1.z * a1.z + a1.w * a1.w;
#pragma unroll
    for (int off = 32; off > 0; off >>= 1) ss += __shfl_xor(ss, off, 64);
    float scale = 1.0f / (sqrtf(ss) + 1e-6f);
    float* op = out + (size_t)row * (D + 1) + 1;
    int d0 = 4 * lane;
    op[d0 + 0] = a0.x * scale; op[d0 + 1] = a0.y * scale;
    op[d0 + 2] = a0.z * scale; op[d0 + 3] = a0.w * scale;
    op[256 + d0 + 0] = a1.x * scale; op[256 + d0 + 1] = a1.y * scale;
    op[256 + d0 + 2] = a1.z * scale; op[256 + d0 + 3] = a1.w * scale;

    // state output column
    if (lane == 0) {
        float vv = base_ws[row & (S - 1)] + state_ws[row];
        out[(size_t)row * (D + 1)] =
            signf(vv) * expf(fabsf(vv) - sm_m[b]) * sm_inv[b];
    }
}

extern "C" void kernel_launch(void* const* d_in, const int* in_sizes, int n_in,
                              void* d_out, int out_size, void* d_ws, size_t ws_size,
                              hipStream_t stream) {
    (void)in_sizes; (void)n_in; (void)out_size; (void)ws_size;
    const float* x          = (const float*)d_in[0];
    const float* init_state = (const float*)d_in[1];
    const float* init_val   = (const float*)d_in[2];
    const float* route_a    = (const float*)d_in[3];
    const float* route_b    = (const float*)d_in[4];
    const float* pair_a     = (const float*)d_in[5];
    const float* pair_b     = (const float*)d_in[6];
    float* out = (float*)d_out;

    float* ws       = (float*)d_ws;
    float* val1     = ws;                             // B*S*D
    float* q        = val1 + (size_t)B * S * D;       // B*S*R
    float* kkT      = q    + (size_t)B * S * R;       // B*R*S
    float* coef     = kkT  + (size_t)B * R * S;       // B*T*K
    int*   binlist  = (int*)(coef + (size_t)B * T * KTOP);   // B*S*CAP
    // --- zero region (one memset): state deltas + bincount + ovf_cnt ---
    float* state_ws = (float*)(binlist + (size_t)B * S * CAP);  // B*S
    int*   bincount = (int*)(state_ws + (size_t)B * S);         // B*S
    int*   ovf_cnt  = bincount + (size_t)B * S;                 // 16 (pad)
    // --- end zero region ---
    int*   ovf_key  = ovf_cnt + 16;                             // OVFCAP
    float* ovf_c    = (float*)(ovf_key + OVFCAP);               // OVFCAP
    float* base_ws  = ovf_c + OVFCAP;                           // S
    float* sm_m     = base_ws + S;                              // B
    float* sm_inv   = sm_m + B;                                 // B

    hipMemsetAsync(state_ws, 0, (size_t)(2 * B * S + 16) * sizeof(int), stream);
    hipLaunchKernelGGL(k_score, dim3(B * T / NT), dim3(512), 0, stream,
                       x, route_a, route_b, state_ws, coef, bincount, binlist,
                       ovf_cnt, ovf_key, ovf_c);
    hipLaunchKernelGGL(k_state_red, dim3(1), dim3(512), 0, stream,
                       init_state, state_ws, base_ws, sm_m, sm_inv);
    hipLaunchKernelGGL(k_accum_qk, dim3(B * S / 4), dim3(256), 0, stream,
                       x, init_val, coef, bincount, binlist,
                       ovf_cnt, ovf_key, ovf_c, pair_a, pair_b, val1, q, kkT);
    hipLaunchKernelGGL(k_pscore_mix, dim3(B * S / NI), dim3(512), 0, stream,
                       q, kkT, val1, base_ws, state_ws, sm_m, sm_inv, out);
}

// Round 7
// 394.109 us; speedup vs baseline: 1.0021x; 1.0021x over previous
//
#include <hip/hip_runtime.h>
#include <cmath>

namespace {
constexpr int B = 8;
constexpr int T = 2048;
constexpr int D = 512;
constexpr int S = 2048;
constexpr int R = 64;
constexpr int KTOP = 16;
constexpr int NT = 8;    // tokens per block in score kernel (512 threads)
constexpr int NI = 8;    // rows per block in pscore kernel (512 threads)
constexpr int CAP = 256;     // bin capacity per (b,slot); overflow -> global list
constexpr int OVFCAP = 32768;

__device__ __forceinline__ float signf(float v) {
    return (v > 0.f) ? 1.f : ((v < 0.f) ? -1.f : 0.f);
}

// Exact top-16 by |value| (ties -> lower index) over a wave-private LDS row of S
// floats. Result: lane k (k<16) gets myg = signed value, myj = index, in exact
// descending (|v|, -j) order. Row contents are preserved on the fast path.
__device__ __forceinline__ void topk16_row(float* __restrict__ row,
                                           unsigned long long* __restrict__ cand,
                                           int lane, float& myg, int& myj) {
    const float4* p4 = (const float4*)row;
    // Phase 1: per-lane abs max over 32 elements
    float lmax = 0.f;
#pragma unroll
    for (int i = 0; i < 8; i++) {
        float4 v = p4[lane + 64 * i];
        lmax = fmaxf(lmax, fmaxf(fmaxf(fabsf(v.x), fabsf(v.y)),
                                 fmaxf(fabsf(v.z), fabsf(v.w))));
    }
    // Phase 2: bitonic sort (descending) of 64 lane maxes; t = 16th largest
    {
        float v = lmax;
#pragma unroll
        for (int size = 2; size <= 64; size <<= 1) {
#pragma unroll
            for (int stride = size >> 1; stride > 0; stride >>= 1) {
                float o = __shfl_xor(v, stride, 64);
                bool takeMax = ((lane & size) == 0) == ((lane & stride) == 0);
                v = takeMax ? fmaxf(v, o) : fminf(v, o);
            }
        }
        lmax = __shfl(v, 15);
    }
    float t = lmax;
    // Phase 3: count candidates with |v| >= t, prefix-sum, compact into cand[]
    int cnt = 0;
#pragma unroll
    for (int i = 0; i < 8; i++) {
        float4 v = p4[lane + 64 * i];
        cnt += (fabsf(v.x) >= t) + (fabsf(v.y) >= t) +
               (fabsf(v.z) >= t) + (fabsf(v.w) >= t);
    }
    int off = cnt;
#pragma unroll
    for (int d = 1; d < 64; d <<= 1) {
        int o = __shfl_up(off, d, 64);
        if (lane >= d) off += o;
    }
    int total = __shfl(off, 63);
    int base = off - cnt;

    if (total <= 64) {
        int pos = base;
#pragma unroll
        for (int i = 0; i < 8; i++) {
            float4 v = p4[lane + 64 * i];
            int jb = 4 * (lane + 64 * i);
            float c[4] = {v.x, v.y, v.z, v.w};
#pragma unroll
            for (int cc = 0; cc < 4; cc++) {
                if (fabsf(c[cc]) >= t) {
                    unsigned ab = __float_as_uint(c[cc]) & 0x7fffffffu;
                    cand[pos++] = ((unsigned long long)ab << 11) |
                                  (unsigned)(2047 - (jb + cc));
                }
            }
        }
        // Phase 4: bitonic sort (descending) of up to 64 u64 keys
        unsigned long long key = (lane < total) ? cand[lane] : 0ull;
#pragma unroll
        for (int size = 2; size <= 64; size <<= 1) {
#pragma unroll
            for (int stride = size >> 1; stride > 0; stride >>= 1) {
                unsigned long long o = __shfl_xor((long long)key, stride, 64);
                bool takeMax = ((lane & size) == 0) == ((lane & stride) == 0);
                key = (takeMax == (key > o)) ? key : o;
            }
        }
        myg = 0.f; myj = 0;
        if (lane < KTOP) {
            myj = 2047 - (int)(key & 2047ull);
            myg = row[myj];
        }
    } else {
        // Fallback (rare): 16 rounds of full-row argmax with removal
        myg = 0.f; myj = 0;
        for (int k = 0; k < KTOP; k++) {
            float bv = -1.f, bs = 0.f; int bj = 0;
#pragma unroll
            for (int i = 0; i < 8; i++) {
                float4 v = p4[lane + 64 * i];
                int jb = 4 * (lane + 64 * i);
                { float a = fabsf(v.x); if (a > bv) { bv = a; bs = v.x; bj = jb; } }
                { float a = fabsf(v.y); if (a > bv) { bv = a; bs = v.y; bj = jb + 1; } }
                { float a = fabsf(v.z); if (a > bv) { bv = a; bs = v.z; bj = jb + 2; } }
                { float a = fabsf(v.w); if (a > bv) { bv = a; bs = v.w; bj = jb + 3; } }
            }
#pragma unroll
            for (int off2 = 32; off2 > 0; off2 >>= 1) {
                float ov = __shfl_xor(bv, off2, 64);
                float os = __shfl_xor(bs, off2, 64);
                int   oj = __shfl_xor(bj, off2, 64);
                if (ov > bv || (ov == bv && oj < bj)) { bv = ov; bs = os; bj = oj; }
            }
            if (lane == k) { myg = bs; myj = bj; }
            if (lane == 0) row[bj] = 0.f;
        }
    }
}
} // namespace

// ---------- score stage: route scores -> per-wave topk -> bin lists ----------
// state_ws holds DELTAS only (memset 0 before this kernel).
// Overflow (bin > CAP) goes to a global list consumed by k_accum_qk.
__global__ void __launch_bounds__(512, 4) k_score(const float* __restrict__ x,
                                                  const float* __restrict__ route_a,
                                                  const float* __restrict__ route_b,
                                                  float* __restrict__ state_ws,
                                                  float* __restrict__ coef,
                                                  int* __restrict__ bincount,
                                                  int* __restrict__ binlist,
                                                  int* __restrict__ ovf_cnt,
                                                  int* __restrict__ ovf_key,
                                                  float* __restrict__ ovf_c) {
    __shared__ __align__(16) char smem[NT * S * 4]; // 64 KB: xs -> red4 -> sc
    __shared__ __align__(16) float xr[NT][R];       // 2 KB
    __shared__ unsigned long long cand[NT][64];     // 4 KB
    float (*sc)[S] = (float(*)[S])smem;
    float (*xs)[D] = (float(*)[D])smem;             // overlay (x-load + acc read)
    float (*red4)[512] = (float(*)[512])smem;       // overlay (reduction only)

    int tid = threadIdx.x;
    int lane = tid & 63, wv = tid >> 6;
    int blk = ((blockIdx.x & 7) << 8) | (blockIdx.x >> 3);  // XCD k <-> b=k
    int tb = blk * NT;              // global token base (block never straddles b)
    int b = tb >> 11;               // T = 2048
    int t0 = tb & (T - 1);

    // load 8 x rows into LDS (1024 float4, 512 threads)
    {
        const float4* xg = (const float4*)(x + (size_t)tb * D);
        float4* xls = (float4*)smem;
        xls[tid] = xg[tid];
        xls[tid + 512] = xg[tid + 512];
    }
    __syncthreads();

    // x inverse norm for this wave's token, from LDS (x is read once, here)
    float xinv;
    {
        const float4* xst = (const float4*)&xs[wv][0];
        float4 x0 = xst[lane], x1 = xst[lane + 64];
        float ssx = x0.x * x0.x + x0.y * x0.y + x0.z * x0.z + x0.w * x0.w
                  + x1.x * x1.x + x1.y * x1.y + x1.z * x1.z + x1.w * x1.w;
#pragma unroll
        for (int off = 32; off > 0; off >>= 1) ssx += __shfl_xor(ssx, off, 64);
        xinv = 1.0f / (sqrtf(ssx) + 1e-6f);
    }

    // xr = x . route_a  (wave wv covers d in [wv*64, wv*64+64), r = lane)
    {
        int r = lane;
        float acc[NT];
#pragma unroll
        for (int tt = 0; tt < NT; tt++) acc[tt] = 0.f;
        for (int d0 = wv * 64; d0 < wv * 64 + 64; d0 += 4) {
            float a0 = route_a[(size_t)(d0 + 0) * R + r];
            float a1 = route_a[(size_t)(d0 + 1) * R + r];
            float a2 = route_a[(size_t)(d0 + 2) * R + r];
            float a3 = route_a[(size_t)(d0 + 3) * R + r];
#pragma unroll
            for (int tt = 0; tt < NT; tt++) {
                float4 xv = *(const float4*)&xs[tt][d0];
                acc[tt] += xv.x * a0 + xv.y * a1 + xv.z * a2 + xv.w * a3;
            }
        }
        __syncthreads();   // xs dead; red4 region writable
#pragma unroll
        for (int tt = 0; tt < NT; tt++) red4[tt][tid] = acc[tt];
        __syncthreads();
        {
            int tt2 = tid >> 6, r2 = tid & 63;
            float s = 0.f;
#pragma unroll
            for (int g = 0; g < 8; g++) s += red4[tt2][g * 64 + r2];
            xr[tt2][r2] = s;
        }
        __syncthreads();   // red4 dead; sc writable
    }

    // scores = xr . route_b  (float4 over s; 512 threads cover S/4 = 512)
    {
        const float4* rb4 = (const float4*)route_b;
        int j4 = tid;
        float4 acc[NT];
#pragma unroll
        for (int tt = 0; tt < NT; tt++) acc[tt] = make_float4(0.f, 0.f, 0.f, 0.f);
        for (int r0 = 0; r0 < R; r0 += 4) {
            float4 xv[NT];
#pragma unroll
            for (int tt = 0; tt < NT; tt++) xv[tt] = *(const float4*)&xr[tt][r0];
#define SCORE_STEP(dr, comp)                                                   \
            {                                                                  \
                float4 bv = rb4[(size_t)(r0 + dr) * (S / 4) + j4];             \
                _Pragma("unroll")                                              \
                for (int tt = 0; tt < NT; tt++) {                              \
                    float c = xv[tt].comp;                                     \
                    acc[tt].x += c * bv.x; acc[tt].y += c * bv.y;              \
                    acc[tt].z += c * bv.z; acc[tt].w += c * bv.w;              \
                }                                                              \
            }
            SCORE_STEP(0, x) SCORE_STEP(1, y) SCORE_STEP(2, z) SCORE_STEP(3, w)
#undef SCORE_STEP
        }
#pragma unroll
        for (int tt = 0; tt < NT; tt++)
            ((float4*)&sc[tt][0])[j4] = acc[tt];
    }
    __syncthreads();

    // ---- per-wave from here: wave wv owns token tt = wv ----
    int tt = wv;
    int tloc = t0 + tt;
    int tglob = tb + tt;

    float myg; int myj;
    topk16_row(&sc[tt][0], &cand[wv][0], lane, myg, myj);

    // signed-abs-softmax over the 16 winners (lane k holds winner k)
    float m = __shfl(fabsf(myg), 0);
    float e = (lane < KTOP) ? expf(fabsf(myg) - m) : 0.f;
    float esum = e;
#pragma unroll
    for (int off = 8; off > 0; off >>= 1) esum += __shfl_xor(esum, off, 64);
    esum = __shfl(esum, 0);
    float w = signf(myg) * e / esum;
    float coefv = w * xinv;

    if (lane < KTOP) {
        float sp = (myg > 20.f) ? myg : log1pf(expf(myg));
        atomicAdd(&state_ws[(size_t)b * S + myj], sp);
        int pos = atomicAdd(&bincount[(size_t)b * S + myj], 1);
        if (pos < CAP) {
            binlist[((size_t)b * S + myj) * CAP + pos] = (tloc << 4) | lane;
            coef[(size_t)tglob * KTOP + lane] = coefv;
        } else {
            // overflow (essentially never): append to global list
            int i = atomicAdd(ovf_cnt, 1);
            if (i < OVFCAP) {
                ovf_key[i] = ((b * S + myj) << 11) | tloc;  // 14b row | 11b tloc
                ovf_c[i] = coefv;
            }
        }
    }
}

// ---------- accum+qk: val1 = unit_norm(base + sum c*x); q/kkT projections ----
// Gather loop uses 4-wide load batching (accumulated in original order ->
// bit-identical).
__global__ void __launch_bounds__(256) k_accum_qk(const float* __restrict__ x,
                                                  const float* __restrict__ init_val,
                                                  const float* __restrict__ coef,
                                                  const int* __restrict__ bincount,
                                                  const int* __restrict__ binlist,
                                                  const int* __restrict__ ovf_cnt,
                                                  const int* __restrict__ ovf_key,
                                                  const float* __restrict__ ovf_c,
                                                  const float* __restrict__ pair_a,
                                                  const float* __restrict__ pair_b,
                                                  float* __restrict__ val1,
                                                  float* __restrict__ q,
                                                  float* __restrict__ kkT) {
    __shared__ __align__(16) float vrow[4][D];    // 8 KB
    __shared__ float redq[4][256];                // 4 KB
    __shared__ float redk[4][256];                // 4 KB

    int tid = threadIdx.x;
    int lane = tid & 63, wv = tid >> 6;
    int blk = ((blockIdx.x & 7) << 9) | (blockIdx.x >> 3);  // XCD k <-> b=k
    int rowbase = blk * 4;
    int row = rowbase + wv;             // row = b*S + s
    int b = row >> 11;                  // S = 2048
    int s_idx = row & (S - 1);
    int sbase = rowbase & (S - 1);

    // base = unit_norm(init_val[s]) computed in-register
    const float4* src = (const float4*)(init_val + (size_t)s_idx * D);
    float4 a0 = src[lane], a1 = src[lane + 64];
    {
        float ss0 = a0.x * a0.x + a0.y * a0.y + a0.z * a0.z + a0.w * a0.w
                  + a1.x * a1.x + a1.y * a1.y + a1.z * a1.z + a1.w * a1.w;
#pragma unroll
        for (int off = 32; off > 0; off >>= 1) ss0 += __shfl_xor(ss0, off, 64);
        float bsc = 1.0f / (sqrtf(ss0) + 1e-6f);
        a0.x *= bsc; a0.y *= bsc; a0.z *= bsc; a0.w *= bsc;
        a1.x *= bsc; a1.y *= bsc; a1.z *= bsc; a1.w *= bsc;
    }

    const float* xb = x + (size_t)b * T * D;
    int n = bincount[row]; if (n > CAP) n = CAP;
    const int* lp = binlist + (size_t)row * CAP;
    for (int base = 0; base < n; base += 64) {
        int mm = n - base; if (mm > 64) mm = 64;
        int ent = 0; float cc = 0.f;
        if (lane < mm) {
            ent = lp[base + lane];
            cc = coef[((size_t)b * T + (ent >> 4)) * KTOP + (ent & 15)];
        }
        int k = 0;
        // 4-wide batches: 8 float4 loads in flight, accumulate in k-order
        for (; k + 4 <= mm; k += 4) {
            int j0 = __shfl(ent, k) >> 4,     j1 = __shfl(ent, k + 1) >> 4;
            int j2 = __shfl(ent, k + 2) >> 4, j3 = __shfl(ent, k + 3) >> 4;
            float c0 = __shfl(cc, k),     c1 = __shfl(cc, k + 1);
            float c2 = __shfl(cc, k + 2), c3 = __shfl(cc, k + 3);
            const float4* p0 = (const float4*)(xb + (size_t)j0 * D);
            const float4* p1 = (const float4*)(xb + (size_t)j1 * D);
            const float4* p2 = (const float4*)(xb + (size_t)j2 * D);
            const float4* p3 = (const float4*)(xb + (size_t)j3 * D);
            float4 u0 = p0[lane], u1 = p0[lane + 64];
            float4 u2 = p1[lane], u3 = p1[lane + 64];
            float4 u4 = p2[lane], u5 = p2[lane + 64];
            float4 u6 = p3[lane], u7 = p3[lane + 64];
            a0.x += c0 * u0.x; a0.y += c0 * u0.y; a0.z += c0 * u0.z; a0.w += c0 * u0.w;
            a1.x += c0 * u1.x; a1.y += c0 * u1.y; a1.z += c0 * u1.z; a1.w += c0 * u1.w;
            a0.x += c1 * u2.x; a0.y += c1 * u2.y; a0.z += c1 * u2.z; a0.w += c1 * u2.w;
            a1.x += c1 * u3.x; a1.y += c1 * u3.y; a1.z += c1 * u3.z; a1.w += c1 * u3.w;
            a0.x += c2 * u4.x; a0.y += c2 * u4.y; a0.z += c2 * u4.z; a0.w += c2 * u4.w;
            a1.x += c2 * u5.x; a1.y += c2 * u5.y; a1.z += c2 * u5.z; a1.w += c2 * u5.w;
            a0.x += c3 * u6.x; a0.y += c3 * u6.y; a0.z += c3 * u6.z; a0.w += c3 * u6.w;
            a1.x += c3 * u7.x; a1.y += c3 * u7.y; a1.z += c3 * u7.z; a1.w += c3 * u7.w;
        }
        for (; k < mm; k++) {
            int j0 = __shfl(ent, k) >> 4;
            float c = __shfl(cc, k);
            const float4* p0 = (const float4*)(xb + (size_t)j0 * D);
            float4 u0 = p0[lane], u1 = p0[lane + 64];
            a0.x += c * u0.x; a0.y += c * u0.y; a0.z += c * u0.z; a0.w += c * u0.w;
            a1.x += c * u1.x; a1.y += c * u1.y; a1.z += c * u1.z; a1.w += c * u1.w;
        }
    }

    // overflow list (cold path; one uniform load when empty)
    int oc = *ovf_cnt; if (oc > OVFCAP) oc = OVFCAP;
    for (int i = 0; i < oc; i++) {
        int key = ovf_key[i];
        if ((key >> 11) == row) {
            float c = ovf_c[i];
            int tg = ((row >> 11) << 11) | (key & 2047);   // b*T + tloc
            const float4* xp4 = (const float4*)(x + (size_t)tg * D);
            float4 v0 = xp4[lane], v1 = xp4[lane + 64];
            a0.x += c * v0.x; a0.y += c * v0.y; a0.z += c * v0.z; a0.w += c * v0.w;
            a1.x += c * v1.x; a1.y += c * v1.y; a1.z += c * v1.z; a1.w += c * v1.w;
        }
    }

    float ss = a0.x * a0.x + a0.y * a0.y + a0.z * a0.z + a0.w * a0.w
             + a1.x * a1.x + a1.y * a1.y + a1.z * a1.z + a1.w * a1.w;
#pragma unroll
    for (int off = 32; off > 0; off >>= 1) ss += __shfl_xor(ss, off, 64);
    float sc = 1.0f / (sqrtf(ss) + 1e-6f);
    a0.x *= sc; a0.y *= sc; a0.z *= sc; a0.w *= sc;
    a1.x *= sc; a1.y *= sc; a1.z *= sc; a1.w *= sc;
    float4* vp4 = (float4*)(val1 + (size_t)row * D);
    vp4[lane] = a0; vp4[lane + 64] = a1;

    // ---- stage rows to LDS, then q/kT projection (k_qk structure, NR=4) ----
    {
        float4* vr = (float4*)&vrow[wv][0];
        vr[lane] = a0; vr[lane + 64] = a1;
    }
    __syncthreads();

    int r = lane, grp = wv;
    float accq[4], acck[4];
#pragma unroll
    for (int rr = 0; rr < 4; rr++) { accq[rr] = 0.f; acck[rr] = 0.f; }
    for (int d0 = grp * 128; d0 < grp * 128 + 128; d0 += 4) {
#pragma unroll
        for (int dd = 0; dd < 4; dd++) {
            float a  = pair_a[(size_t)(d0 + dd) * R + r];
            float bb = pair_b[(size_t)(d0 + dd) * R + r];
#pragma unroll
            for (int rr = 0; rr < 4; rr++) {
                float v = vrow[rr][d0 + dd];
                accq[rr] += v * a;
                acck[rr] += v * bb;
            }
        }
    }
#pragma unroll
    for (int rr = 0; rr < 4; rr++) {
        redq[rr][tid] = accq[rr];
        redk[rr][tid] = acck[rr];
    }
    __syncthreads();
    {
        int rr = tid >> 6, r2 = tid & 63;
        float qv = redq[rr][r2] + redq[rr][64 + r2] +
                   redq[rr][128 + r2] + redq[rr][192 + r2];
        float kv = redk[rr][r2] + redk[rr][64 + r2] +
                   redk[rr][128 + r2] + redk[rr][192 + r2];
        q[(size_t)(rowbase + rr) * R + r2] = qv;
        kkT[((size_t)b * R + r2) * S + (sbase + rr)] = kv;
    }
}

// ---------- state reduce: base softmax + per-b (m, 1/sum) of base+delta ------
// One block, 512 threads.
__global__ void __launch_bounds__(512) k_state_red(const float* __restrict__ init_state,
                                                   const float* __restrict__ state_ws,
                                                   float* base_ws,
                                                   float* sm_m, float* sm_inv) {
    __shared__ float red[16];
    __shared__ float base_lds[S];   // 8 KB
    int tid = threadIdx.x, lane = tid & 63, wv = tid >> 6;

    // Phase A: base = sign * softmax(|init_state|)  (2048 values, 4 per thread)
    float4 v = ((const float4*)init_state)[tid];
    float m = fmaxf(fmaxf(fabsf(v.x), fabsf(v.y)), fmaxf(fabsf(v.z), fabsf(v.w)));
#pragma unroll
    for (int off = 32; off > 0; off >>= 1) m = fmaxf(m, __shfl_xor(m, off, 64));
    if (lane == 0) red[wv] = m;
    __syncthreads();
    float M = red[0];
#pragma unroll
    for (int i = 1; i < 8; i++) M = fmaxf(M, red[i]);
    __syncthreads();
    float s = expf(fabsf(v.x) - M) + expf(fabsf(v.y) - M) +
              expf(fabsf(v.z) - M) + expf(fabsf(v.w) - M);
#pragma unroll
    for (int off = 32; off > 0; off >>= 1) s += __shfl_xor(s, off, 64);
    if (lane == 0) red[wv] = s;
    __syncthreads();
    float SUM = 0.f;
#pragma unroll
    for (int i = 0; i < 8; i++) SUM += red[i];
    float inv = 1.0f / SUM;
    float4 bo;
    bo.x = signf(v.x) * expf(fabsf(v.x) - M) * inv;
    bo.y = signf(v.y) * expf(fabsf(v.y) - M) * inv;
    bo.z = signf(v.z) * expf(fabsf(v.z) - M) * inv;
    bo.w = signf(v.w) * expf(fabsf(v.w) - M) * inv;
    ((float4*)base_ws)[tid] = bo;
    ((float4*)base_lds)[tid] = bo;
    __syncthreads();

    // Phase B: wave wv = b; combined = base + delta; per-b max & expsum
    int b = wv;
    const float4* dp = (const float4*)(state_ws + (size_t)b * S);
    const float4* bp = (const float4*)base_lds;
    float4 c[8];
    float vm = 0.f;
#pragma unroll
    for (int i = 0; i < 8; i++) {
        float4 dv = dp[lane + 64 * i];
        float4 bv = bp[lane + 64 * i];
        c[i].x = bv.x + dv.x; c[i].y = bv.y + dv.y;
        c[i].z = bv.z + dv.z; c[i].w = bv.w + dv.w;
        vm = fmaxf(vm, fmaxf(fmaxf(fabsf(c[i].x), fabsf(c[i].y)),
                             fmaxf(fabsf(c[i].z), fabsf(c[i].w))));
    }
#pragma unroll
    for (int off = 32; off > 0; off >>= 1) vm = fmaxf(vm, __shfl_xor(vm, off, 64));
    float sum = 0.f;
#pragma unroll
    for (int i = 0; i < 8; i++) {
        sum += expf(fabsf(c[i].x) - vm) + expf(fabsf(c[i].y) - vm) +
               expf(fabsf(c[i].z) - vm) + expf(fabsf(c[i].w) - vm);
    }
#pragma unroll
    for (int off = 32; off > 0; off >>= 1) sum += __shfl_xor(sum, off, 64);
    if (lane == 0) { sm_m[b] = vm; sm_inv[b] = 1.0f / sum; }
}

// ---------- pscore+mix: p = q.kT, topk, gather neighbors, write out ----------
// out is written with NONTEMPORAL stores: it is never re-read, and letting it
// allocate in L2 evicts the val1 slab (4 MB/XCD) that the 16-neighbor gather
// needs resident. Gather loop is the simple unrolled form (compiler pipelines).
__global__ void __launch_bounds__(512) k_pscore_mix(const float* __restrict__ q,
                                                    const float* __restrict__ kkT,
                                                    const float* __restrict__ val1,
                                                    const float* __restrict__ base_ws,
                                                    const float* __restrict__ state_ws,
                                                    const float* __restrict__ sm_m,
                                                    const float* __restrict__ sm_inv,
                                                    float* __restrict__ out) {
    __shared__ __align__(16) float prow[NI][S];   // 64 KB
    __shared__ __align__(16) float qrow[NI][R];   // 2 KB
    __shared__ unsigned long long cand[NI][64];   // 4 KB

    int tid = threadIdx.x;
    int lane = tid & 63, wv = tid >> 6;
    int blk = ((blockIdx.x & 7) << 8) | (blockIdx.x >> 3);  // XCD k <-> b=k
    int ibase = blk * NI;            // global row base (never straddles b)
    int b = ibase >> 11;             // S = 2048

    {
        int rr = tid >> 6, r = tid & 63;
        qrow[rr][r] = q[(size_t)(ibase + rr) * R + r];
    }
    __syncthreads();

    // p rows (float4 over j; kkT slice reused by 8 rows)
    {
        const float4* kk4 = (const float4*)(kkT + (size_t)b * R * S);
        int j4 = tid;                // 512 threads cover S/4 = 512
        float4 acc[NI];
#pragma unroll
        for (int rr = 0; rr < NI; rr++) acc[rr] = make_float4(0.f, 0.f, 0.f, 0.f);
        for (int r0 = 0; r0 < R; r0 += 4) {
            float4 qv[NI];
#pragma unroll
            for (int rr = 0; rr < NI; rr++) qv[rr] = *(const float4*)&qrow[rr][r0];
#define P_STEP(dr, comp)                                                       \
            {                                                                  \
                float4 kv = kk4[(size_t)(r0 + dr) * (S / 4) + j4];             \
                _Pragma("unroll")                                              \
                for (int rr = 0; rr < NI; rr++) {                              \
                    float c = qv[rr].comp;                                     \
                    acc[rr].x += c * kv.x; acc[rr].y += c * kv.y;              \
                    acc[rr].z += c * kv.z; acc[rr].w += c * kv.w;              \
                }                                                              \
            }
            P_STEP(0, x) P_STEP(1, y) P_STEP(2, z) P_STEP(3, w)
#undef P_STEP
        }
#pragma unroll
        for (int rr = 0; rr < NI; rr++)
            ((float4*)&prow[rr][0])[j4] = acc[rr];
    }
    __syncthreads();

    // ---- per-wave topk on row ibase + wv (8 waves, 8 rows) ----
    int row = ibase + wv;
    float myg; int myj;
    topk16_row(&prow[wv][0], &cand[wv][0], lane, myg, myj);

    float m = __shfl(fabsf(myg), 0);
    float e = (lane < KTOP) ? expf(fabsf(myg) - m) : 0.f;
    float esum = e;
#pragma unroll
    for (int off = 8; off > 0; off >>= 1) esum += __shfl_xor(esum, off, 64);
    esum = __shfl(esum, 0);
    float myw = signf(myg) * e / esum;

    // ---- mix: gather neighbors, residual add, unit-norm, full out row ----
    const float* vb = val1 + (size_t)b * S * D;
    const float4* self4 = (const float4*)(val1 + (size_t)row * D);
    float4 a0 = self4[lane], a1 = self4[lane + 64];
#pragma unroll
    for (int k = 0; k < KTOP; k++) {
        int j = __shfl(myj, k);
        float w = __shfl(myw, k);
        const float4* nb4 = (const float4*)(vb + (size_t)j * D);
        float4 v0 = nb4[lane], v1 = nb4[lane + 64];
        a0.x += w * v0.x; a0.y += w * v0.y; a0.z += w * v0.z; a0.w += w * v0.w;
        a1.x += w * v1.x; a1.y += w * v1.y; a1.z += w * v1.z; a1.w += w * v1.w;
    }
    float ss = a0.x * a0.x + a0.y * a0.y + a0.z * a0.z + a0.w * a0.w
             + a1.x * a1.x + a1.y * a1.y + a1.z * a1.z + a1.w * a1.w;
#pragma unroll
    for (int off = 32; off > 0; off >>= 1) ss += __shfl_xor(ss, off, 64);
    float scale = 1.0f / (sqrtf(ss) + 1e-6f);
    float* op = out + (size_t)row * (D + 1) + 1;
    int d0 = 4 * lane;
    __builtin_nontemporal_store(a0.x * scale, &op[d0 + 0]);
    __builtin_nontemporal_store(a0.y * scale, &op[d0 + 1]);
    __builtin_nontemporal_store(a0.z * scale, &op[d0 + 2]);
    __builtin_nontemporal_store(a0.w * scale, &op[d0 + 3]);
    __builtin_nontemporal_store(a1.x * scale, &op[256 + d0 + 0]);
    __builtin_nontemporal_store(a1.y * scale, &op[256 + d0 + 1]);
    __builtin_nontemporal_store(a1.z * scale, &op[256 + d0 + 2]);
    __builtin_nontemporal_store(a1.w * scale, &op[256 + d0 + 3]);

    // state output column
    if (lane == 0) {
        float vv = base_ws[row & (S - 1)] + state_ws[row];
        __builtin_nontemporal_store(
            signf(vv) * expf(fabsf(vv) - sm_m[b]) * sm_inv[b],
            &out[(size_t)row * (D + 1)]);
    }
}

extern "C" void kernel_launch(void* const* d_in, const int* in_sizes, int n_in,
                              void* d_out, int out_size, void* d_ws, size_t ws_size,
                              hipStream_t stream) {
    (void)in_sizes; (void)n_in; (void)out_size; (void)ws_size;
    const float* x          = (const float*)d_in[0];
    const float* init_state = (const float*)d_in[1];
    const float* init_val   = (const float*)d_in[2];
    const float* route_a    = (const float*)d_in[3];
    const float* route_b    = (const float*)d_in[4];
    const float* pair_a     = (const float*)d_in[5];
    const float* pair_b     = (const float*)d_in[6];
    float* out = (float*)d_out;

    float* ws       = (float*)d_ws;
    float* val1     = ws;                             // B*S*D
    float* q        = val1 + (size_t)B * S * D;       // B*S*R
    float* kkT      = q    + (size_t)B * S * R;       // B*R*S
    float* coef     = kkT  + (size_t)B * R * S;       // B*T*K
    int*   binlist  = (int*)(coef + (size_t)B * T * KTOP);   // B*S*CAP
    // --- zero region (one memset): state deltas + bincount + ovf_cnt ---
    float* state_ws = (float*)(binlist + (size_t)B * S * CAP);  // B*S
    int*   bincount = (int*)(state_ws + (size_t)B * S);         // B*S
    int*   ovf_cnt  = bincount + (size_t)B * S;                 // 16 (pad)
    // --- end zero region ---
    int*   ovf_key  = ovf_cnt + 16;                             // OVFCAP
    float* ovf_c    = (float*)(ovf_key + OVFCAP);               // OVFCAP
    float* base_ws  = ovf_c + OVFCAP;                           // S
    float* sm_m     = base_ws + S;                              // B
    float* sm_inv   = sm_m + B;                                 // B

    hipMemsetAsync(state_ws, 0, (size_t)(2 * B * S + 16) * sizeof(int), stream);
    hipLaunchKernelGGL(k_score, dim3(B * T / NT), dim3(512), 0, stream,
                       x, route_a, route_b, state_ws, coef, bincount, binlist,
                       ovf_cnt, ovf_key, ovf_c);
    hipLaunchKernelGGL(k_state_red, dim3(1), dim3(512), 0, stream,
                       init_state, state_ws, base_ws, sm_m, sm_inv);
    hipLaunchKernelGGL(k_accum_qk, dim3(B * S / 4), dim3(256), 0, stream,
                       x, init_val, coef, bincount, binlist,
                       ovf_cnt, ovf_key, ovf_c, pair_a, pair_b, val1, q, kkT);
    hipLaunchKernelGGL(k_pscore_mix, dim3(B * S / NI), dim3(512), 0, stream,
                       q, kkT, val1, base_ws, state_ws, sm_m, sm_inv, out);
}

// Round 9
// 371.048 us; speedup vs baseline: 1.0644x; 1.0622x over previous
//
#include <hip/hip_runtime.h>
#include <cmath>

namespace {
constexpr int B = 8;
constexpr int T = 2048;
constexpr int D = 512;
constexpr int S = 2048;
constexpr int R = 64;
constexpr int KTOP = 16;
constexpr int NT = 8;    // tokens per block in score kernel (512 threads)
constexpr int NI = 8;    // rows per block in pscore kernel (512 threads)
constexpr int NA = 8;    // rows per block in accum_qk kernel (512 threads)
constexpr int CAP = 256;     // bin capacity per (b,slot); overflow -> global list
constexpr int OVFCAP = 32768;

typedef float vfloat4 __attribute__((ext_vector_type(4)));  // clang vector type
                                                            // (nontemporal-able)

__device__ __forceinline__ float signf(float v) {
    return (v > 0.f) ? 1.f : ((v < 0.f) ? -1.f : 0.f);
}

// Exact top-16 by |value| (ties -> lower index) over a wave-private LDS row of S
// floats. Result: lane k (k<16) gets myg = signed value, myj = index, in exact
// descending (|v|, -j) order. Row contents are preserved on the fast path.
__device__ __forceinline__ void topk16_row(float* __restrict__ row,
                                           unsigned long long* __restrict__ cand,
                                           int lane, float& myg, int& myj) {
    const float4* p4 = (const float4*)row;
    // Phase 1: per-lane abs max over 32 elements
    float lmax = 0.f;
#pragma unroll
    for (int i = 0; i < 8; i++) {
        float4 v = p4[lane + 64 * i];
        lmax = fmaxf(lmax, fmaxf(fmaxf(fabsf(v.x), fabsf(v.y)),
                                 fmaxf(fabsf(v.z), fabsf(v.w))));
    }
    // Phase 2: bitonic sort (descending) of 64 lane maxes; t = 16th largest
    {
        float v = lmax;
#pragma unroll
        for (int size = 2; size <= 64; size <<= 1) {
#pragma unroll
            for (int stride = size >> 1; stride > 0; stride >>= 1) {
                float o = __shfl_xor(v, stride, 64);
                bool takeMax = ((lane & size) == 0) == ((lane & stride) == 0);
                v = takeMax ? fmaxf(v, o) : fminf(v, o);
            }
        }
        lmax = __shfl(v, 15);
    }
    float t = lmax;
    // Phase 3: count candidates with |v| >= t, prefix-sum, compact into cand[]
    int cnt = 0;
#pragma unroll
    for (int i = 0; i < 8; i++) {
        float4 v = p4[lane + 64 * i];
        cnt += (fabsf(v.x) >= t) + (fabsf(v.y) >= t) +
               (fabsf(v.z) >= t) + (fabsf(v.w) >= t);
    }
    int off = cnt;
#pragma unroll
    for (int d = 1; d < 64; d <<= 1) {
        int o = __shfl_up(off, d, 64);
        if (lane >= d) off += o;
    }
    int total = __shfl(off, 63);
    int base = off - cnt;

    if (total <= 64) {
        int pos = base;
#pragma unroll
        for (int i = 0; i < 8; i++) {
            float4 v = p4[lane + 64 * i];
            int jb = 4 * (lane + 64 * i);
            float c[4] = {v.x, v.y, v.z, v.w};
#pragma unroll
            for (int cc = 0; cc < 4; cc++) {
                if (fabsf(c[cc]) >= t) {
                    unsigned ab = __float_as_uint(c[cc]) & 0x7fffffffu;
                    cand[pos++] = ((unsigned long long)ab << 11) |
                                  (unsigned)(2047 - (jb + cc));
                }
            }
        }
        // Phase 4: bitonic sort (descending) of up to 64 u64 keys
        unsigned long long key = (lane < total) ? cand[lane] : 0ull;
#pragma unroll
        for (int size = 2; size <= 64; size <<= 1) {
#pragma unroll
            for (int stride = size >> 1; stride > 0; stride >>= 1) {
                unsigned long long o = __shfl_xor((long long)key, stride, 64);
                bool takeMax = ((lane & size) == 0) == ((lane & stride) == 0);
                key = (takeMax == (key > o)) ? key : o;
            }
        }
        myg = 0.f; myj = 0;
        if (lane < KTOP) {
            myj = 2047 - (int)(key & 2047ull);
            myg = row[myj];
        }
    } else {
        // Fallback (rare): 16 rounds of full-row argmax with removal
        myg = 0.f; myj = 0;
        for (int k = 0; k < KTOP; k++) {
            float bv = -1.f, bs = 0.f; int bj = 0;
#pragma unroll
            for (int i = 0; i < 8; i++) {
                float4 v = p4[lane + 64 * i];
                int jb = 4 * (lane + 64 * i);
                { float a = fabsf(v.x); if (a > bv) { bv = a; bs = v.x; bj = jb; } }
                { float a = fabsf(v.y); if (a > bv) { bv = a; bs = v.y; bj = jb + 1; } }
                { float a = fabsf(v.z); if (a > bv) { bv = a; bs = v.z; bj = jb + 2; } }
                { float a = fabsf(v.w); if (a > bv) { bv = a; bs = v.w; bj = jb + 3; } }
            }
#pragma unroll
            for (int off2 = 32; off2 > 0; off2 >>= 1) {
                float ov = __shfl_xor(bv, off2, 64);
                float os = __shfl_xor(bs, off2, 64);
                int   oj = __shfl_xor(bj, off2, 64);
                if (ov > bv || (ov == bv && oj < bj)) { bv = ov; bs = os; bj = oj; }
            }
            if (lane == k) { myg = bs; myj = bj; }
            if (lane == 0) row[bj] = 0.f;
        }
    }
}
} // namespace

// ---------- score stage: route scores -> per-wave topk -> bin lists ----------
// state_ws holds DELTAS only (memset 0 before this kernel).
// Overflow (bin > CAP) goes to a global list consumed by k_accum_qk.
__global__ void __launch_bounds__(512, 4) k_score(const float* __restrict__ x,
                                                  const float* __restrict__ route_a,
                                                  const float* __restrict__ route_b,
                                                  float* __restrict__ state_ws,
                                                  float* __restrict__ coef,
                                                  int* __restrict__ bincount,
                                                  int* __restrict__ binlist,
                                                  int* __restrict__ ovf_cnt,
                                                  int* __restrict__ ovf_key,
                                                  float* __restrict__ ovf_c) {
    __shared__ __align__(16) char smem[NT * S * 4]; // 64 KB: xs -> red4 -> sc
    __shared__ __align__(16) float xr[NT][R];       // 2 KB
    __shared__ unsigned long long cand[NT][64];     // 4 KB
    float (*sc)[S] = (float(*)[S])smem;
    float (*xs)[D] = (float(*)[D])smem;             // overlay (x-load + acc read)
    float (*red4)[512] = (float(*)[512])smem;       // overlay (reduction only)

    int tid = threadIdx.x;
    int lane = tid & 63, wv = tid >> 6;
    int blk = ((blockIdx.x & 7) << 8) | (blockIdx.x >> 3);  // XCD k <-> b=k
    int tb = blk * NT;              // global token base (block never straddles b)
    int b = tb >> 11;               // T = 2048
    int t0 = tb & (T - 1);

    // load 8 x rows into LDS (1024 float4, 512 threads)
    {
        const float4* xg = (const float4*)(x + (size_t)tb * D);
        float4* xls = (float4*)smem;
        xls[tid] = xg[tid];
        xls[tid + 512] = xg[tid + 512];
    }
    __syncthreads();

    // x inverse norm for this wave's token, from LDS (x is read once, here)
    float xinv;
    {
        const float4* xst = (const float4*)&xs[wv][0];
        float4 x0 = xst[lane], x1 = xst[lane + 64];
        float ssx = x0.x * x0.x + x0.y * x0.y + x0.z * x0.z + x0.w * x0.w
                  + x1.x * x1.x + x1.y * x1.y + x1.z * x1.z + x1.w * x1.w;
#pragma unroll
        for (int off = 32; off > 0; off >>= 1) ssx += __shfl_xor(ssx, off, 64);
        xinv = 1.0f / (sqrtf(ssx) + 1e-6f);
    }

    // xr = x . route_a  (wave wv covers d in [wv*64, wv*64+64), r = lane)
    {
        int r = lane;
        float acc[NT];
#pragma unroll
        for (int tt = 0; tt < NT; tt++) acc[tt] = 0.f;
        for (int d0 = wv * 64; d0 < wv * 64 + 64; d0 += 4) {
            float a0 = route_a[(size_t)(d0 + 0) * R + r];
            float a1 = route_a[(size_t)(d0 + 1) * R + r];
            float a2 = route_a[(size_t)(d0 + 2) * R + r];
            float a3 = route_a[(size_t)(d0 + 3) * R + r];
#pragma unroll
            for (int tt = 0; tt < NT; tt++) {
                float4 xv = *(const float4*)&xs[tt][d0];
                acc[tt] += xv.x * a0 + xv.y * a1 + xv.z * a2 + xv.w * a3;
            }
        }
        __syncthreads();   // xs dead; red4 region writable
#pragma unroll
        for (int tt = 0; tt < NT; tt++) red4[tt][tid] = acc[tt];
        __syncthreads();
        {
            int tt2 = tid >> 6, r2 = tid & 63;
            float s = 0.f;
#pragma unroll
            for (int g = 0; g < 8; g++) s += red4[tt2][g * 64 + r2];
            xr[tt2][r2] = s;
        }
        __syncthreads();   // red4 dead; sc writable
    }

    // scores = xr . route_b  (float4 over s; 512 threads cover S/4 = 512)
    {
        const float4* rb4 = (const float4*)route_b;
        int j4 = tid;
        float4 acc[NT];
#pragma unroll
        for (int tt = 0; tt < NT; tt++) acc[tt] = make_float4(0.f, 0.f, 0.f, 0.f);
        for (int r0 = 0; r0 < R; r0 += 4) {
            float4 xv[NT];
#pragma unroll
            for (int tt = 0; tt < NT; tt++) xv[tt] = *(const float4*)&xr[tt][r0];
#define SCORE_STEP(dr, comp)                                                   \
            {                                                                  \
                float4 bv = rb4[(size_t)(r0 + dr) * (S / 4) + j4];             \
                _Pragma("unroll")                                              \
                for (int tt = 0; tt < NT; tt++) {                              \
                    float c = xv[tt].comp;                                     \
                    acc[tt].x += c * bv.x; acc[tt].y += c * bv.y;              \
                    acc[tt].z += c * bv.z; acc[tt].w += c * bv.w;              \
                }                                                              \
            }
            SCORE_STEP(0, x) SCORE_STEP(1, y) SCORE_STEP(2, z) SCORE_STEP(3, w)
#undef SCORE_STEP
        }
#pragma unroll
        for (int tt = 0; tt < NT; tt++)
            ((float4*)&sc[tt][0])[j4] = acc[tt];
    }
    __syncthreads();

    // ---- per-wave from here: wave wv owns token tt = wv ----
    int tt = wv;
    int tloc = t0 + tt;
    int tglob = tb + tt;

    float myg; int myj;
    topk16_row(&sc[tt][0], &cand[wv][0], lane, myg, myj);

    // signed-abs-softmax over the 16 winners (lane k holds winner k)
    float m = __shfl(fabsf(myg), 0);
    float e = (lane < KTOP) ? expf(fabsf(myg) - m) : 0.f;
    float esum = e;
#pragma unroll
    for (int off = 8; off > 0; off >>= 1) esum += __shfl_xor(esum, off, 64);
    esum = __shfl(esum, 0);
    float w = signf(myg) * e / esum;
    float coefv = w * xinv;

    if (lane < KTOP) {
        float sp = (myg > 20.f) ? myg : log1pf(expf(myg));
        atomicAdd(&state_ws[(size_t)b * S + myj], sp);
        int pos = atomicAdd(&bincount[(size_t)b * S + myj], 1);
        if (pos < CAP) {
            binlist[((size_t)b * S + myj) * CAP + pos] = (tloc << 4) | lane;
            coef[(size_t)tglob * KTOP + lane] = coefv;
        } else {
            // overflow (essentially never): append to global list
            int i = atomicAdd(ovf_cnt, 1);
            if (i < OVFCAP) {
                ovf_key[i] = ((b * S + myj) << 11) | tloc;  // 14b row | 11b tloc
                ovf_c[i] = coefv;
            }
        }
    }
}

// ---------- accum+qk: val1 = unit_norm(base + sum c*x); q/kkT projections ----
// NA=8 rows @ 512 threads: halves per-row pair_a/pair_b L2 traffic vs NA=4.
// The qk projection runs as two 256-thread halves, each replicating the
// original 4-row structure exactly (same grp partition, same 4-partial
// reduce order) -> bit-identical q/kkT. init_val is loaded nontemporally
// (pure stream; keeps the gathered x slab L2-resident).
__global__ void __launch_bounds__(512) k_accum_qk(const float* __restrict__ x,
                                                  const float* __restrict__ init_val,
                                                  const float* __restrict__ coef,
                                                  const int* __restrict__ bincount,
                                                  const int* __restrict__ binlist,
                                                  const int* __restrict__ ovf_cnt,
                                                  const int* __restrict__ ovf_key,
                                                  const float* __restrict__ ovf_c,
                                                  const float* __restrict__ pair_a,
                                                  const float* __restrict__ pair_b,
                                                  float* __restrict__ val1,
                                                  float* __restrict__ q,
                                                  float* __restrict__ kkT) {
    __shared__ __align__(16) float vrow[NA][D];    // 16 KB
    __shared__ float redq[NA][256];                // 8 KB
    __shared__ float redk[NA][256];                // 8 KB

    int tid = threadIdx.x;
    int lane = tid & 63, wv = tid >> 6;
    int blk = ((blockIdx.x & 7) << 8) | (blockIdx.x >> 3);  // 2048 blocks
    int rowbase = blk * NA;
    int row = rowbase + wv;             // row = b*S + s (wave wv owns one row)
    int b = row >> 11;                  // S = 2048
    int s_idx = row & (S - 1);
    int sbase = rowbase & (S - 1);

    // base = unit_norm(init_val[s]) computed in-register (nontemporal stream)
    const vfloat4* src = (const vfloat4*)(init_val + (size_t)s_idx * D);
    vfloat4 b0 = __builtin_nontemporal_load(&src[lane]);
    vfloat4 b1 = __builtin_nontemporal_load(&src[lane + 64]);
    float4 a0 = make_float4(b0.x, b0.y, b0.z, b0.w);
    float4 a1 = make_float4(b1.x, b1.y, b1.z, b1.w);
    {
        float ss0 = a0.x * a0.x + a0.y * a0.y + a0.z * a0.z + a0.w * a0.w
                  + a1.x * a1.x + a1.y * a1.y + a1.z * a1.z + a1.w * a1.w;
#pragma unroll
        for (int off = 32; off > 0; off >>= 1) ss0 += __shfl_xor(ss0, off, 64);
        float bsc = 1.0f / (sqrtf(ss0) + 1e-6f);
        a0.x *= bsc; a0.y *= bsc; a0.z *= bsc; a0.w *= bsc;
        a1.x *= bsc; a1.y *= bsc; a1.z *= bsc; a1.w *= bsc;
    }

    const float* xb = x + (size_t)b * T * D;
    int n = bincount[row]; if (n > CAP) n = CAP;
    const int* lp = binlist + (size_t)row * CAP;
    for (int base = 0; base < n; base += 64) {
        int mm = n - base; if (mm > 64) mm = 64;
        int ent = 0; float cc = 0.f;
        if (lane < mm) {
            ent = lp[base + lane];
            cc = coef[((size_t)b * T + (ent >> 4)) * KTOP + (ent & 15)];
        }
        int k = 0;
        // 4-wide batches: 8 float4 loads in flight, accumulate in k-order
        for (; k + 4 <= mm; k += 4) {
            int j0 = __shfl(ent, k) >> 4,     j1 = __shfl(ent, k + 1) >> 4;
            int j2 = __shfl(ent, k + 2) >> 4, j3 = __shfl(ent, k + 3) >> 4;
            float c0 = __shfl(cc, k),     c1 = __shfl(cc, k + 1);
            float c2 = __shfl(cc, k + 2), c3 = __shfl(cc, k + 3);
            const float4* p0 = (const float4*)(xb + (size_t)j0 * D);
            const float4* p1 = (const float4*)(xb + (size_t)j1 * D);
            const float4* p2 = (const float4*)(xb + (size_t)j2 * D);
            const float4* p3 = (const float4*)(xb + (size_t)j3 * D);
            float4 u0 = p0[lane], u1 = p0[lane + 64];
            float4 u2 = p1[lane], u3 = p1[lane + 64];
            float4 u4 = p2[lane], u5 = p2[lane + 64];
            float4 u6 = p3[lane], u7 = p3[lane + 64];
            a0.x += c0 * u0.x; a0.y += c0 * u0.y; a0.z += c0 * u0.z; a0.w += c0 * u0.w;
            a1.x += c0 * u1.x; a1.y += c0 * u1.y; a1.z += c0 * u1.z; a1.w += c0 * u1.w;
            a0.x += c1 * u2.x; a0.y += c1 * u2.y; a0.z += c1 * u2.z; a0.w += c1 * u2.w;
            a1.x += c1 * u3.x; a1.y += c1 * u3.y; a1.z += c1 * u3.z; a1.w += c1 * u3.w;
            a0.x += c2 * u4.x; a0.y += c2 * u4.y; a0.z += c2 * u4.z; a0.w += c2 * u4.w;
            a1.x += c2 * u5.x; a1.y += c2 * u5.y; a1.z += c2 * u5.z; a1.w += c2 * u5.w;
            a0.x += c3 * u6.x; a0.y += c3 * u6.y; a0.z += c3 * u6.z; a0.w += c3 * u6.w;
            a1.x += c3 * u7.x; a1.y += c3 * u7.y; a1.z += c3 * u7.z; a1.w += c3 * u7.w;
        }
        for (; k < mm; k++) {
            int j0 = __shfl(ent, k) >> 4;
            float c = __shfl(cc, k);
            const float4* p0 = (const float4*)(xb + (size_t)j0 * D);
            float4 u0 = p0[lane], u1 = p0[lane + 64];
            a0.x += c * u0.x; a0.y += c * u0.y; a0.z += c * u0.z; a0.w += c * u0.w;
            a1.x += c * u1.x; a1.y += c * u1.y; a1.z += c * u1.z; a1.w += c * u1.w;
        }
    }

    // overflow list (cold path; one uniform load when empty)
    int oc = *ovf_cnt; if (oc > OVFCAP) oc = OVFCAP;
    for (int i = 0; i < oc; i++) {
        int key = ovf_key[i];
        if ((key >> 11) == row) {
            float c = ovf_c[i];
            int tg = ((row >> 11) << 11) | (key & 2047);   // b*T + tloc
            const float4* xp4 = (const float4*)(x + (size_t)tg * D);
            float4 v0 = xp4[lane], v1 = xp4[lane + 64];
            a0.x += c * v0.x; a0.y += c * v0.y; a0.z += c * v0.z; a0.w += c * v0.w;
            a1.x += c * v1.x; a1.y += c * v1.y; a1.z += c * v1.z; a1.w += c * v1.w;
        }
    }

    float ss = a0.x * a0.x + a0.y * a0.y + a0.z * a0.z + a0.w * a0.w
             + a1.x * a1.x + a1.y * a1.y + a1.z * a1.z + a1.w * a1.w;
#pragma unroll
    for (int off = 32; off > 0; off >>= 1) ss += __shfl_xor(ss, off, 64);
    float sc = 1.0f / (sqrtf(ss) + 1e-6f);
    a0.x *= sc; a0.y *= sc; a0.z *= sc; a0.w *= sc;
    a1.x *= sc; a1.y *= sc; a1.z *= sc; a1.w *= sc;
    float4* vp4 = (float4*)(val1 + (size_t)row * D);
    vp4[lane] = a0; vp4[lane + 64] = a1;

    // ---- stage rows to LDS, then q/kT projection (two 4-row halves) ----
    {
        float4* vr = (float4*)&vrow[wv][0];
        vr[lane] = a0; vr[lane + 64] = a1;
    }
    __syncthreads();

    {
        int t2 = tid & 255;            // thread index within the half
        int half = tid >> 8;           // 0: rows 0-3, 1: rows 4-7
        int r = t2 & 63, grp = t2 >> 6;
        float accq[4], acck[4];
#pragma unroll
        for (int rr = 0; rr < 4; rr++) { accq[rr] = 0.f; acck[rr] = 0.f; }
        for (int d0 = grp * 128; d0 < grp * 128 + 128; d0 += 4) {
#pragma unroll
            for (int dd = 0; dd < 4; dd++) {
                float a  = pair_a[(size_t)(d0 + dd) * R + r];
                float bb = pair_b[(size_t)(d0 + dd) * R + r];
#pragma unroll
                for (int rr = 0; rr < 4; rr++) {
                    float v = vrow[half * 4 + rr][d0 + dd];
                    accq[rr] += v * a;
                    acck[rr] += v * bb;
                }
            }
        }
#pragma unroll
        for (int rr = 0; rr < 4; rr++) {
            redq[half * 4 + rr][t2] = accq[rr];
            redk[half * 4 + rr][t2] = acck[rr];
        }
    }
    __syncthreads();
    {
        int half2 = tid >> 8;          // 0..1
        int rr = (tid >> 6) & 3;       // 0..3
        int r2 = tid & 63;
        int rw = half2 * 4 + rr;
        float qv = redq[rw][r2] + redq[rw][64 + r2] +
                   redq[rw][128 + r2] + redq[rw][192 + r2];
        float kv = redk[rw][r2] + redk[rw][64 + r2] +
                   redk[rw][128 + r2] + redk[rw][192 + r2];
        q[(size_t)(rowbase + rw) * R + r2] = qv;
        kkT[((size_t)b * R + r2) * S + (sbase + rw)] = kv;
    }
}

// ---------- state reduce: base softmax + per-b (m, 1/sum) of base+delta ------
// One block, 512 threads.
__global__ void __launch_bounds__(512) k_state_red(const float* __restrict__ init_state,
                                                   const float* __restrict__ state_ws,
                                                   float* base_ws,
                                                   float* sm_m, float* sm_inv) {
    __shared__ float red[16];
    __shared__ float base_lds[S];   // 8 KB
    int tid = threadIdx.x, lane = tid & 63, wv = tid >> 6;

    // Phase A: base = sign * softmax(|init_state|)  (2048 values, 4 per thread)
    float4 v = ((const float4*)init_state)[tid];
    float m = fmaxf(fmaxf(fabsf(v.x), fabsf(v.y)), fmaxf(fabsf(v.z), fabsf(v.w)));
#pragma unroll
    for (int off = 32; off > 0; off >>= 1) m = fmaxf(m, __shfl_xor(m, off, 64));
    if (lane == 0) red[wv] = m;
    __syncthreads();
    float M = red[0];
#pragma unroll
    for (int i = 1; i < 8; i++) M = fmaxf(M, red[i]);
    __syncthreads();
    float s = expf(fabsf(v.x) - M) + expf(fabsf(v.y) - M) +
              expf(fabsf(v.z) - M) + expf(fabsf(v.w) - M);
#pragma unroll
    for (int off = 32; off > 0; off >>= 1) s += __shfl_xor(s, off, 64);
    if (lane == 0) red[wv] = s;
    __syncthreads();
    float SUM = 0.f;
#pragma unroll
    for (int i = 0; i < 8; i++) SUM += red[i];
    float inv = 1.0f / SUM;
    float4 bo;
    bo.x = signf(v.x) * expf(fabsf(v.x) - M) * inv;
    bo.y = signf(v.y) * expf(fabsf(v.y) - M) * inv;
    bo.z = signf(v.z) * expf(fabsf(v.z) - M) * inv;
    bo.w = signf(v.w) * expf(fabsf(v.w) - M) * inv;
    ((float4*)base_ws)[tid] = bo;
    ((float4*)base_lds)[tid] = bo;
    __syncthreads();

    // Phase B: wave wv = b; combined = base + delta; per-b max & expsum
    int b = wv;
    const float4* dp = (const float4*)(state_ws + (size_t)b * S);
    const float4* bp = (const float4*)base_lds;
    float4 c[8];
    float vm = 0.f;
#pragma unroll
    for (int i = 0; i < 8; i++) {
        float4 dv = dp[lane + 64 * i];
        float4 bv = bp[lane + 64 * i];
        c[i].x = bv.x + dv.x; c[i].y = bv.y + dv.y;
        c[i].z = bv.z + dv.z; c[i].w = bv.w + dv.w;
        vm = fmaxf(vm, fmaxf(fmaxf(fabsf(c[i].x), fabsf(c[i].y)),
                             fmaxf(fabsf(c[i].z), fabsf(c[i].w))));
    }
#pragma unroll
    for (int off = 32; off > 0; off >>= 1) vm = fmaxf(vm, __shfl_xor(vm, off, 64));
    float sum = 0.f;
#pragma unroll
    for (int i = 0; i < 8; i++) {
        sum += expf(fabsf(c[i].x) - vm) + expf(fabsf(c[i].y) - vm) +
               expf(fabsf(c[i].z) - vm) + expf(fabsf(c[i].w) - vm);
    }
#pragma unroll
    for (int off = 32; off > 0; off >>= 1) sum += __shfl_xor(sum, off, 64);
    if (lane == 0) { sm_m[b] = vm; sm_inv[b] = 1.0f / sum; }
}

// ---------- pscore+mix: p = q.kT, topk, gather neighbors, write out ----------
// out is written with NONTEMPORAL stores (never re-read; keeps val1 resident).
__global__ void __launch_bounds__(512) k_pscore_mix(const float* __restrict__ q,
                                                    const float* __restrict__ kkT,
                                                    const float* __restrict__ val1,
                                                    const float* __restrict__ base_ws,
                                                    const float* __restrict__ state_ws,
                                                    const float* __restrict__ sm_m,
                                                    const float* __restrict__ sm_inv,
                                                    float* __restrict__ out) {
    __shared__ __align__(16) float prow[NI][S];   // 64 KB
    __shared__ __align__(16) float qrow[NI][R];   // 2 KB
    __shared__ unsigned long long cand[NI][64];   // 4 KB

    int tid = threadIdx.x;
    int lane = tid & 63, wv = tid >> 6;
    int blk = ((blockIdx.x & 7) << 8) | (blockIdx.x >> 3);  // XCD k <-> b=k
    int ibase = blk * NI;            // global row base (never straddles b)
    int b = ibase >> 11;             // S = 2048

    {
        int rr = tid >> 6, r = tid & 63;
        qrow[rr][r] = q[(size_t)(ibase + rr) * R + r];
    }
    __syncthreads();

    // p rows (float4 over j; kkT slice reused by 8 rows)
    {
        const float4* kk4 = (const float4*)(kkT + (size_t)b * R * S);
        int j4 = tid;                // 512 threads cover S/4 = 512
        float4 acc[NI];
#pragma unroll
        for (int rr = 0; rr < NI; rr++) acc[rr] = make_float4(0.f, 0.f, 0.f, 0.f);
        for (int r0 = 0; r0 < R; r0 += 4) {
            float4 qv[NI];
#pragma unroll
            for (int rr = 0; rr < NI; rr++) qv[rr] = *(const float4*)&qrow[rr][r0];
#define P_STEP(dr, comp)                                                       \
            {                                                                  \
                float4 kv = kk4[(size_t)(r0 + dr) * (S / 4) + j4];             \
                _Pragma("unroll")                                              \
                for (int rr = 0; rr < NI; rr++) {                              \
                    float c = qv[rr].comp;                                     \
                    acc[rr].x += c * kv.x; acc[rr].y += c * kv.y;              \
                    acc[rr].z += c * kv.z; acc[rr].w += c * kv.w;              \
                }                                                              \
            }
            P_STEP(0, x) P_STEP(1, y) P_STEP(2, z) P_STEP(3, w)
#undef P_STEP
        }
#pragma unroll
        for (int rr = 0; rr < NI; rr++)
            ((float4*)&prow[rr][0])[j4] = acc[rr];
    }
    __syncthreads();

    // ---- per-wave topk on row ibase + wv (8 waves, 8 rows) ----
    int row = ibase + wv;
    float myg; int myj;
    topk16_row(&prow[wv][0], &cand[wv][0], lane, myg, myj);

    float m = __shfl(fabsf(myg), 0);
    float e = (lane < KTOP) ? expf(fabsf(myg) - m) : 0.f;
    float esum = e;
#pragma unroll
    for (int off = 8; off > 0; off >>= 1) esum += __shfl_xor(esum, off, 64);
    esum = __shfl(esum, 0);
    float myw = signf(myg) * e / esum;

    // ---- mix: gather neighbors, residual add, unit-norm, full out row ----
    const float* vb = val1 + (size_t)b * S * D;
    const float4* self4 = (const float4*)(val1 + (size_t)row * D);
    float4 a0 = self4[lane], a1 = self4[lane + 64];
#pragma unroll
    for (int k = 0; k < KTOP; k++) {
        int j = __shfl(myj, k);
        float w = __shfl(myw, k);
        const float4* nb4 = (const float4*)(vb + (size_t)j * D);
        float4 v0 = nb4[lane], v1 = nb4[lane + 64];
        a0.x += w * v0.x; a0.y += w * v0.y; a0.z += w * v0.z; a0.w += w * v0.w;
        a1.x += w * v1.x; a1.y += w * v1.y; a1.z += w * v1.z; a1.w += w * v1.w;
    }
    float ss = a0.x * a0.x + a0.y * a0.y + a0.z * a0.z + a0.w * a0.w
             + a1.x * a1.x + a1.y * a1.y + a1.z * a1.z + a1.w * a1.w;
#pragma unroll
    for (int off = 32; off > 0; off >>= 1) ss += __shfl_xor(ss, off, 64);
    float scale = 1.0f / (sqrtf(ss) + 1e-6f);
    float* op = out + (size_t)row * (D + 1) + 1;
    int d0 = 4 * lane;
    __builtin_nontemporal_store(a0.x * scale, &op[d0 + 0]);
    __builtin_nontemporal_store(a0.y * scale, &op[d0 + 1]);
    __builtin_nontemporal_store(a0.z * scale, &op[d0 + 2]);
    __builtin_nontemporal_store(a0.w * scale, &op[d0 + 3]);
    __builtin_nontemporal_store(a1.x * scale, &op[256 + d0 + 0]);
    __builtin_nontemporal_store(a1.y * scale, &op[256 + d0 + 1]);
    __builtin_nontemporal_store(a1.z * scale, &op[256 + d0 + 2]);
    __builtin_nontemporal_store(a1.w * scale, &op[256 + d0 + 3]);

    // state output column
    if (lane == 0) {
        float vv = base_ws[row & (S - 1)] + state_ws[row];
        __builtin_nontemporal_store(
            signf(vv) * expf(fabsf(vv) - sm_m[b]) * sm_inv[b],
            &out[(size_t)row * (D + 1)]);
    }
}

extern "C" void kernel_launch(void* const* d_in, const int* in_sizes, int n_in,
                              void* d_out, int out_size, void* d_ws, size_t ws_size,
                              hipStream_t stream) {
    (void)in_sizes; (void)n_in; (void)out_size; (void)ws_size;
    const float* x          = (const float*)d_in[0];
    const float* init_state = (const float*)d_in[1];
    const float* init_val   = (const float*)d_in[2];
    const float* route_a    = (const float*)d_in[3];
    const float* route_b    = (const float*)d_in[4];
    const float* pair_a     = (const float*)d_in[5];
    const float* pair_b     = (const float*)d_in[6];
    float* out = (float*)d_out;

    float* ws       = (float*)d_ws;
    float* val1     = ws;                             // B*S*D
    float* q        = val1 + (size_t)B * S * D;       // B*S*R
    float* kkT      = q    + (size_t)B * S * R;       // B*R*S
    float* coef     = kkT  + (size_t)B * R * S;       // B*T*K
    int*   binlist  = (int*)(coef + (size_t)B * T * KTOP);   // B*S*CAP
    // --- zero region (one memset): state deltas + bincount + ovf_cnt ---
    float* state_ws = (float*)(binlist + (size_t)B * S * CAP);  // B*S
    int*   bincount = (int*)(state_ws + (size_t)B * S);         // B*S
    int*   ovf_cnt  = bincount + (size_t)B * S;                 // 16 (pad)
    // --- end zero region ---
    int*   ovf_key  = ovf_cnt + 16;                             // OVFCAP
    float* ovf_c    = (float*)(ovf_key + OVFCAP);               // OVFCAP
    float* base_ws  = ovf_c + OVFCAP;                           // S
    float* sm_m     = base_ws + S;                              // B
    float* sm_inv   = sm_m + B;                                 // B

    (void)hipMemsetAsync(state_ws, 0, (size_t)(2 * B * S + 16) * sizeof(int), stream);
    hipLaunchKernelGGL(k_score, dim3(B * T / NT), dim3(512), 0, stream,
                       x, route_a, route_b, state_ws, coef, bincount, binlist,
                       ovf_cnt, ovf_key, ovf_c);
    hipLaunchKernelGGL(k_state_red, dim3(1), dim3(512), 0, stream,
                       init_state, state_ws, base_ws, sm_m, sm_inv);
    hipLaunchKernelGGL(k_accum_qk, dim3(B * S / NA), dim3(512), 0, stream,
                       x, init_val, coef, bincount, binlist,
                       ovf_cnt, ovf_key, ovf_c, pair_a, pair_b, val1, q, kkT);
    hipLaunchKernelGGL(k_pscore_mix, dim3(B * S / NI), dim3(512), 0, stream,
                       q, kkT, val1, base_ws, state_ws, sm_m, sm_inv, out);
}